// Round 6
// baseline (7197.585 us; speedup 1.0000x reference)
//
#include <hip/hip_runtime.h>
#include <hip/hip_bf16.h>

#define T_STEPS 800
#define BATCH   32
#define FEAT    161
#define UNITS   1024
#define CLIPV   20.0f

typedef __attribute__((ext_vector_type(8))) short short8;
typedef __attribute__((ext_vector_type(4))) float f32x4;
typedef unsigned short u16;
typedef unsigned int   u32;
typedef unsigned long long u64;

__device__ __forceinline__ float bf16_f(u16 u) {
    return __uint_as_float(((u32)u) << 16);
}
__device__ __forceinline__ u16 bf16_rn(float x) {
    __hip_bfloat16 b = __float2bfloat16(x);
    return *(u16*)&b;
}
__device__ __forceinline__ u64 ld_agent_u64(const u64* p) {
    return __hip_atomic_load(p, __ATOMIC_RELAXED, __HIP_MEMORY_SCOPE_AGENT);
}
__device__ __forceinline__ void st_agent_u64(u64* p, u64 v) {
    __hip_atomic_store(p, v, __ATOMIC_RELAXED, __HIP_MEMORY_SCOPE_AGENT);
}
__device__ __forceinline__ short8 ld_b16x8(const u16* p) {
    union { u64 q[2]; short8 v; } u;
    u.q[0] = ld_agent_u64((const u64*)p);
    u.q[1] = ld_agent_u64((const u64*)p + 1);
    return u.v;
}

// ---------------------------------------------------------------------------
// zero the tagged h double-buffer: 2 x 64 x 1024 u64. tag 0 | value 0.0f = 0.
__global__ __launch_bounds__(256) void init_ws(u64* htag) {
    int gid = blockIdx.x * 256 + threadIdx.x;          // 16384 threads
    for (int i = gid; i < 2 * 64 * UNITS; i += 64 * 256) htag[i] = 0ull;
}

// ---------------------------------------------------------------------------
// Ut splits: U[k][u] fp32 -> Ut1/2/3[u][k] bf16 (hi/mid/lo, 24-bit total)
__global__ __launch_bounds__(256) void u_split_t(const float* __restrict__ U,
                                                 u16* __restrict__ Ut1,
                                                 u16* __restrict__ Ut2,
                                                 u16* __restrict__ Ut3) {
    __shared__ float tile[32][33];
    int bx = blockIdx.x, by = blockIdx.y;
    int lx = threadIdx.x & 31;
    int ly4 = (threadIdx.x >> 5) * 4;
    #pragma unroll
    for (int j = 0; j < 4; ++j)
        tile[ly4 + j][lx] = U[(size_t)(by * 32 + ly4 + j) * UNITS + bx * 32 + lx];
    __syncthreads();
    #pragma unroll
    for (int j = 0; j < 4; ++j) {
        float x = tile[lx][ly4 + j];
        size_t o = (size_t)(bx * 32 + ly4 + j) * UNITS + by * 32 + lx;
        u16 s1 = bf16_rn(x);  float r1 = x - bf16_f(s1);
        u16 s2 = bf16_rn(r1); float r2 = r1 - bf16_f(s2);
        u16 s3 = bf16_rn(r2);
        Ut1[o] = s1; Ut2[o] = s2; Ut3[o] = s3;
    }
}

// ---------------------------------------------------------------------------
__global__ __launch_bounds__(256) void xw_gemm(const float* __restrict__ inp,
                                               const float* __restrict__ W,
                                               const float* __restrict__ bias,
                                               float* __restrict__ xW) {
    __shared__ float xs[8 * FEAT];
    int t = blockIdx.x;
    int b0 = blockIdx.y * 8;
    int tid = threadIdx.x;

    for (int i = tid; i < 8 * FEAT; i += 256) {
        int j = i / FEAT;
        int f = i - j * FEAT;
        xs[i] = inp[((size_t)(b0 + j) * T_STEPS + t) * FEAT + f];
    }
    __syncthreads();

    float bv[4];
    #pragma unroll
    for (int c = 0; c < 4; ++c) bv[c] = bias[tid + c * 256];

    float acc[8][4];
    #pragma unroll
    for (int j = 0; j < 8; ++j)
        #pragma unroll
        for (int c = 0; c < 4; ++c) acc[j][c] = bv[c];

    for (int f = 0; f < FEAT; ++f) {
        float w0 = W[(size_t)f * UNITS + tid];
        float w1 = W[(size_t)f * UNITS + tid + 256];
        float w2 = W[(size_t)f * UNITS + tid + 512];
        float w3 = W[(size_t)f * UNITS + tid + 768];
        #pragma unroll
        for (int j = 0; j < 8; ++j) {
            float xv = xs[j * FEAT + f];
            acc[j][0] += xv * w0;
            acc[j][1] += xv * w1;
            acc[j][2] += xv * w2;
            acc[j][3] += xv * w3;
        }
    }

    #pragma unroll
    for (int j = 0; j < 8; ++j)
        #pragma unroll
        for (int c = 0; c < 4; ++c)
            xW[((size_t)t * BATCH + b0 + j) * UNITS + tid + c * 256] = acc[j][c];
}

// ---------------------------------------------------------------------------
// Tagged-dataflow MFMA scan. 128 blocks x 512 threads (8 waves).
// Block (rg 0..3, ug 0..31): rows [rg*16,+16) (row = dir*32+b), cols [ug*32,+32).
// h exchanged as (tag<<32 | fp32) in one 8B atomic word: the reader's poll IS
// the data load (self-validating; no flags, no barriers, no vmcnt-drain on the
// critical path). Double buffer; WAR-safe transitively (a writer reaching step
// t+1 has READ tag-(t+1) words from every block of its rg, which are stored
// only after those blocks completed their step-t loads).
// Wave kq handles k-slice [kq*128,+128) (4 MFMA k-steps, one writer block per
// k-step). Epilogue distributed: all 8 waves dump partials to LDS; each of the
// 512 threads reduces + tags + stores exactly one C element.
__global__ __launch_bounds__(512) void rnn_scan(
        const float* __restrict__ xW,
        const u16* __restrict__ Ut1, const u16* __restrict__ Ut2,
        const u16* __restrict__ Ut3,
        u64* __restrict__ htag, float* __restrict__ out) {
    __shared__ f32x4 red[16][64];   // 16 KB: [wave*2+nq][lane]

    const int tid  = threadIdx.x;
    const int bk   = blockIdx.x;
    const int lane = tid & 63;
    const int kq   = tid >> 6;       // 0..7
    const int quad = lane >> 4;      // 0..3
    const int n16  = lane & 15;
    const int rg   = bk & 3;
    const int ug   = bk >> 2;
    const int R0   = rg * 16;
    const int u0   = ug * 32;
    const int dir  = rg >> 1;

    // epilogue element for this thread: C[row][col] of the 16x32 tile
    const int erow = tid >> 5;       // 0..15
    const int ecol = tid & 31;       // 0..31
    const int enq  = ecol >> 4;
    const int el16 = (erow >> 2) * 16 + (ecol & 15);
    const int ereg = erow & 3;
    const int eb   = (R0 + erow) & 31;           // batch row for xW
    const size_t edst = (size_t)(R0 + erow) * UNITS + u0 + ecol;

    // --- B fragments: U splits, 96 VGPRs, loaded once (atomic -> pinned) ---
    short8 bfr[4][2][3];
    #pragma unroll
    for (int ks = 0; ks < 4; ++ks) {
        const int koff = kq * 128 + ks * 32 + quad * 8;
        #pragma unroll
        for (int nq = 0; nq < 2; ++nq) {
            const size_t ub = (size_t)(u0 + nq * 16 + n16) * UNITS + koff;
            bfr[ks][nq][0] = ld_b16x8(Ut1 + ub);
            bfr[ks][nq][1] = ld_b16x8(Ut2 + ub);
            bfr[ks][nq][2] = ld_b16x8(Ut3 + ub);
        }
    }

    const size_t HS = (size_t)64 * UNITS;        // u64 elems per buffer

    for (int t = 0; t < T_STEPS; ++t) {
        const size_t sb = (size_t)(t & 1) * HS;
        const size_t db = sb ^ HS;
        const u32 tagv = (u32)t;

        // xW prefetch for this thread's epilogue element
        const int xt = dir ? (T_STEPS - 1 - t) : t;
        const float xwv = xW[(size_t)xt * (BATCH * UNITS) +
                             (size_t)eb * UNITS + u0 + ecol];

        // ---- A: tagged poll-loads (the poll IS the data load) + MFMA ----
        f32x4 acc[2][2] = {{{0.f,0.f,0.f,0.f},{0.f,0.f,0.f,0.f}},
                           {{0.f,0.f,0.f,0.f},{0.f,0.f,0.f,0.f}}};
        #pragma unroll
        for (int ks = 0; ks < 4; ++ks) {
            const u64* src = htag + sb + (size_t)(R0 + n16) * UNITS +
                             kq * 128 + ks * 32 + quad * 8;
            u64 p[8];
            for (;;) {
                #pragma unroll
                for (int j = 0; j < 8; ++j) p[j] = ld_agent_u64(src + j);
                bool ok = true;
                #pragma unroll
                for (int j = 0; j < 8; ++j) ok &= ((u32)(p[j] >> 32) == tagv);
                if (__all(ok)) break;
            }
            short8 a1, a2, a3;
            #pragma unroll
            for (int j = 0; j < 8; ++j) {
                u32 xb = (u32)p[j];
                float x = __uint_as_float(xb);
                u16 s1 = (u16)(xb >> 16);
                float r1 = x - bf16_f(s1);
                u16 s2 = (u16)(__float_as_uint(r1) >> 16);
                float r2 = r1 - bf16_f(s2);
                u16 s3 = (u16)(__float_as_uint(r2) >> 16);
                a1[j] = (short)s1; a2[j] = (short)s2; a3[j] = (short)s3;
            }
            #pragma unroll
            for (int nq = 0; nq < 2; ++nq) {
                acc[nq][0] = __builtin_amdgcn_mfma_f32_16x16x32_bf16(a1, bfr[ks][nq][0], acc[nq][0], 0, 0, 0);
                acc[nq][1] = __builtin_amdgcn_mfma_f32_16x16x32_bf16(a2, bfr[ks][nq][0], acc[nq][1], 0, 0, 0);
                acc[nq][0] = __builtin_amdgcn_mfma_f32_16x16x32_bf16(a1, bfr[ks][nq][1], acc[nq][0], 0, 0, 0);
                acc[nq][1] = __builtin_amdgcn_mfma_f32_16x16x32_bf16(a2, bfr[ks][nq][1], acc[nq][1], 0, 0, 0);
                acc[nq][0] = __builtin_amdgcn_mfma_f32_16x16x32_bf16(a1, bfr[ks][nq][2], acc[nq][0], 0, 0, 0);
                acc[nq][1] = __builtin_amdgcn_mfma_f32_16x16x32_bf16(a3, bfr[ks][nq][0], acc[nq][1], 0, 0, 0);
            }
        }

        // ---- all waves dump partials; 512 threads reduce+store 1 elem each --
        red[kq * 2 + 0][lane] = acc[0][0] + acc[0][1];
        red[kq * 2 + 1][lane] = acc[1][0] + acc[1][1];
        __syncthreads();

        float s = 0.f;
        #pragma unroll
        for (int w = 0; w < 8; ++w) s += red[w * 2 + enq][el16][ereg];
        float a = fminf(fmaxf(s + xwv, 0.f), CLIPV);
        st_agent_u64(htag + db + edst,
                     ((u64)(u32)(t + 1) << 32) | (u64)__float_as_uint(a));
        __syncthreads();   // red[] reusable; drains stores before next poll
    }

    // ---- output: out = hf + hb. Final tag = 800, buffer 0. Self-validating.
    if (rg < 2) {
        const u64* pf = htag + (size_t)(R0 + erow) * UNITS + u0 + ecol;
        const u64* pb = htag + (size_t)(R0 + erow + 32) * UNITS + u0 + ecol;
        u64 vf, vb;
        while ((u32)((vf = ld_agent_u64(pf)) >> 32) != (u32)T_STEPS) {}
        while ((u32)((vb = ld_agent_u64(pb)) >> 32) != (u32)T_STEPS) {}
        out[(size_t)(R0 + erow) * UNITS + u0 + ecol] =
            __uint_as_float((u32)vf) + __uint_as_float((u32)vb);
    }
}

// ---------------------------------------------------------------------------
extern "C" void kernel_launch(void* const* d_in, const int* in_sizes, int n_in,
                              void* d_out, int out_size, void* d_ws, size_t ws_size,
                              hipStream_t stream) {
    const float* inp  = (const float*)d_in[0];   // [32][800][161]
    const float* W    = (const float*)d_in[1];   // [161][1024]
    const float* U    = (const float*)d_in[2];   // [1024][1024]
    const float* bias = (const float*)d_in[3];   // [1024]
    float* out = (float*)d_out;                  // [32][1024]

    u16*   Ut1 = (u16*)d_ws;                              // 3 x 2 MB bf16 planes
    u16*   Ut2 = Ut1 + (size_t)UNITS * UNITS;
    u16*   Ut3 = Ut2 + (size_t)UNITS * UNITS;
    float* xW  = (float*)(Ut3 + (size_t)UNITS * UNITS);   // 104.9 MB
    u64*   htag = (u64*)(xW + (size_t)T_STEPS * BATCH * UNITS);  // 2 x 512 KB

    init_ws<<<64, 256, 0, stream>>>(htag);
    u_split_t<<<dim3(32, 32), 256, 0, stream>>>(U, Ut1, Ut2, Ut3);
    xw_gemm<<<dim3(800, 4), 256, 0, stream>>>(inp, W, bias, xW);

    void* args[] = {(void*)&xW, (void*)&Ut1, (void*)&Ut2, (void*)&Ut3,
                    (void*)&htag, (void*)&out};
    hipLaunchCooperativeKernel((const void*)rnn_scan, dim3(128), dim3(512),
                               args, 0, stream);
}